// Round 15
// baseline (125.527 us; speedup 1.0000x reference)
//
#include <hip/hip_runtime.h>

typedef _Float16 f16;
typedef _Float16 f16x8 __attribute__((ext_vector_type(8)));
typedef _Float16 f16x4 __attribute__((ext_vector_type(4)));
typedef float f32x4 __attribute__((ext_vector_type(4)));

#define BM 128
#define BN 128
#define BKK 32

#define MFMA16(a, b, c) __builtin_amdgcn_mfma_f32_16x16x32_f16((a), (b), (c), 0, 0, 0)

typedef __attribute__((address_space(3))) void lds_void;
typedef const __attribute__((address_space(1))) void g_void;
__device__ __forceinline__ void async_copy16(void* lds, const void* g) {
    __builtin_amdgcn_global_load_lds((g_void*)g, (lds_void*)lds, 16, 0, 0);
}

// ---------------------------------------------------------------------------
// prep: fused (a) wtrans Wqkv+Wo (b) RoPE trig table (c) x fp32->fp16
//       (d) bpos[t] = (seq_id<<16)|pos token table.
__global__ __launch_bounds__(256) void prep(
    const float* __restrict__ x, f16* __restrict__ xh, int T,
    const float* __restrict__ Wqkv, const float* __restrict__ Wo,
    f16* __restrict__ wqkvT, f16* __restrict__ woT,
    float2* __restrict__ tab, int Spad,
    const int* __restrict__ cu, int Bn, int* __restrict__ bpos) {
    int id = blockIdx.x;
    int tid = threadIdx.x;
    if (id < 1024) {
        __shared__ f16 tile[64][65];
        const float* in; f16* out; int N, bx, by;
        if (id < 768) { in = Wqkv; out = wqkvT; N = 3072; bx = id % 48; by = id / 48; }
        else { int j = id - 768; in = Wo; out = woT; N = 1024; bx = j % 16; by = j / 16; }
        const int K = 1024;
        int n0 = bx * 64, k0 = by * 64;
        int c = tid & 63, rb = tid >> 6;
#pragma unroll
        for (int it = 0; it < 16; ++it) {
            int r = rb + it * 4;
            tile[r][c] = (f16)in[(size_t)(k0 + r) * N + n0 + c];
        }
        __syncthreads();
#pragma unroll
        for (int it = 0; it < 16; ++it) {
            int rr = rb + it * 4;
            out[(size_t)(n0 + rr) * K + k0 + c] = tile[c][rr];
        }
    } else if (id < 1152) {
        int idx = (id - 1024) * 256 + tid;
        if (idx < Spad * 32) {
            int pos = idx >> 5, i = idx & 31;
            float inv = exp2f((float)i * (-13.287712379549449f / 32.f));
            float sn, cs;
            __sincosf((float)pos * inv, &sn, &cs);
            tab[idx] = make_float2(cs, sn);
        }
    } else if (id < 1152 + T) {
        int i4 = ((id - 1152) * 256 + tid) * 4;
        if (i4 < T * 1024) {
            float4 v = *reinterpret_cast<const float4*>(x + i4);
            f16x4 o;
            o[0] = (f16)v.x; o[1] = (f16)v.y; o[2] = (f16)v.z; o[3] = (f16)v.w;
            *reinterpret_cast<f16x4*>(xh + i4) = o;
        }
    } else {
        int t = (id - 1152 - T) * 256 + tid;
        if (t < T) {
            int b = 0, pos = t;
            for (int q = 0; q < Bn; ++q) {
                int lo = cu[q], hi = cu[q + 1];
                if (t >= lo && t < hi) { b = q; pos = t - lo; break; }
            }
            bpos[t] = (b << 16) | pos;
        }
    }
}

// ---------------------------------------------------------------------------
// shared m97-structure GEMM main loop with bank-conflict XOR swizzle.
// LDS[row][chunk] holds G[row][chunk ^ ((row>>1)&3)] (16B chunks, involution):
// staging source pre-swizzled, fragment reads swizzle back.
__device__ __forceinline__ void gemm_core(
    const f16* __restrict__ A, const f16* __restrict__ Bt,
    int M, int N, int K, int bx, int by, int tid,
    f16 lA[2][BM * BKK], f16 lB[2][BN * BKK], f32x4 acc[4][4]) {
    int lane = tid & 63, w = tid >> 6;
    int lr = lane & 15, lg = lane >> 4;
    int wm = (w & 1) * 64, wn = (w >> 1) * 64;
    int srow = tid >> 2;
    int scol = (((tid & 3) ^ ((tid >> 3) & 3)) * 8);   // pre-swizzled source chunk
    const f16* ga0 = A  + (size_t)min(by * BM + srow,      M - 1) * K + scol;
    const f16* ga1 = A  + (size_t)min(by * BM + 64 + srow, M - 1) * K + scol;
    const f16* gb0 = Bt + (size_t)min(bx * BN + srow,      N - 1) * K + scol;
    const f16* gb1 = Bt + (size_t)min(bx * BN + 64 + srow, N - 1) * K + scol;
    int NT = K / BKK;
    int csw = (lg ^ ((lr >> 1) & 3)) * 8;              // swizzled read chunk
#define STAGE(curb, kt) do {                                        \
        int ko = (kt) * BKK;                                        \
        async_copy16(&lA[curb][w * 512],        ga0 + ko);          \
        async_copy16(&lA[curb][2048 + w * 512], ga1 + ko);          \
        async_copy16(&lB[curb][w * 512],        gb0 + ko);          \
        async_copy16(&lB[curb][2048 + w * 512], gb1 + ko);          \
    } while (0)
    STAGE(0, 0);
    __syncthreads();
    int cur = 0;
    for (int kt = 0; kt < NT; ++kt) {
        if (kt + 1 < NT) STAGE(cur ^ 1, kt + 1);
        f16x8 af[4], bf[4];
#pragma unroll
        for (int i = 0; i < 4; ++i) {
            af[i] = *reinterpret_cast<const f16x8*>(&lA[cur][(wm + i * 16 + lr) * BKK + csw]);
            bf[i] = *reinterpret_cast<const f16x8*>(&lB[cur][(wn + i * 16 + lr) * BKK + csw]);
        }
#pragma unroll
        for (int mi = 0; mi < 4; ++mi)
#pragma unroll
            for (int ni = 0; ni < 4; ++ni)
                acc[mi][ni] = MFMA16(af[mi], bf[ni], acc[mi][ni]);
        __syncthreads();
        cur ^= 1;
    }
#undef STAGE
}

// ---------------------------------------------------------------------------
// QKV GEMM with fused bias + RoPE + head-major scatter epilogue (bpos table).
__global__ __launch_bounds__(256) void gemm_qkv(
    const f16* __restrict__ A, const f16* __restrict__ Bt,
    const float* __restrict__ bias, const int* __restrict__ bpos,
    const float2* __restrict__ tab, int M, int Spad,
    f16* __restrict__ qh2, f16* __restrict__ kh2, f16* __restrict__ vt, int nbx) {
    __shared__ f16 lA[2][BM * BKK];
    __shared__ f16 lB[2][BN * BKK];
    int tid = threadIdx.x;
    int nwg = gridDim.x, wg = blockIdx.x;
    int tile = ((nwg & 7) == 0) ? ((wg & 7) * (nwg >> 3) + (wg >> 3)) : wg;
    int by = tile / nbx, bx = tile % nbx;

    f32x4 acc[4][4] = {};
    gemm_core(A, Bt, M, 3072, 1024, bx, by, tid, lA, lB, acc);

    int lane = tid & 63, w = tid >> 6;
    int lr = lane & 15, lg = lane >> 4;
    int wm = (w & 1) * 64, wn = (w >> 1) * 64;
    int colwave = bx * BN + wn;          // multiple of 64
    int sect = colwave >> 10;            // 0=q, 1=k, 2=v
    int h = (colwave & 1023) >> 6;
    float bv[4];
#pragma unroll
    for (int ni = 0; ni < 4; ++ni) bv[ni] = bias[colwave + ni * 16 + lr];

#pragma unroll
    for (int mi = 0; mi < 4; ++mi) {
        int row0 = by * BM + wm + mi * 16 + 4 * lg;
        if (row0 >= M) continue;
        if (sect == 2) {
            int v0 = bpos[row0];
            int b0 = v0 >> 16, p0 = v0 & 0xffff;
            bool pack = (row0 + 3 < M) && ((p0 & 3) == 0) && ((bpos[row0 + 3] >> 16) == b0);
            if (pack) {
                size_t vb = (size_t)(b0 * 16 + h) * 64;
#pragma unroll
                for (int ni = 0; ni < 4; ++ni) {
                    int d = ni * 16 + lr;
                    f16x4 ov;
#pragma unroll
                    for (int r = 0; r < 4; ++r) ov[r] = (f16)(acc[mi][ni][r] + bv[ni]);
                    *reinterpret_cast<f16x4*>(vt + (vb + d) * Spad + p0) = ov;
                }
            } else {
                for (int r = 0; r < 4; ++r) {
                    int row = row0 + r;
                    if (row >= M) break;
                    int v = bpos[row];
                    int b = v >> 16, pos = v & 0xffff;
                    size_t vb = (size_t)(b * 16 + h) * 64;
#pragma unroll
                    for (int ni = 0; ni < 4; ++ni)
                        vt[(vb + ni * 16 + lr) * Spad + pos] = (f16)(acc[mi][ni][r] + bv[ni]);
                }
            }
        } else {
            float sc = sect == 0 ? 0.125f : 1.f;
            f16* dstbase = sect == 0 ? qh2 : kh2;
            for (int r = 0; r < 4; ++r) {
                int row = row0 + r;
                if (row >= M) break;
                int v = bpos[row];
                int b = v >> 16, pos = v & 0xffff;
                const float2* tb = tab + pos * 32;
                f16* dst = dstbase + ((size_t)(b * 16 + h) * Spad + pos) * 64;
#pragma unroll
                for (int p = 0; p < 2; ++p) {
                    int i = p * 16 + lr;
                    float2 csn = tb[i];
                    float v1 = acc[mi][p][r] + bv[p];
                    float v2 = acc[mi][p + 2][r] + bv[p + 2];
                    dst[i]      = (f16)((v1 * csn.x - v2 * csn.y) * sc);
                    dst[i + 32] = (f16)((v2 * csn.x + v1 * csn.y) * sc);
                }
            }
        }
    }
}

// ---------------------------------------------------------------------------
// out-proj GEMM: plain epilogue, fp32 out + bias.
__global__ __launch_bounds__(256) void gemm_out(
    const f16* __restrict__ A, const f16* __restrict__ Bt,
    const float* __restrict__ bias, float* __restrict__ Cf,
    int M, int N, int K, int nbx) {
    __shared__ f16 lA[2][BM * BKK];
    __shared__ f16 lB[2][BN * BKK];
    int tid = threadIdx.x;
    int nwg = gridDim.x, wg = blockIdx.x;
    int tile = ((nwg & 7) == 0) ? ((wg & 7) * (nwg >> 3) + (wg >> 3)) : wg;
    int by = tile / nbx, bx = tile % nbx;

    f32x4 acc[4][4] = {};
    gemm_core(A, Bt, M, N, K, bx, by, tid, lA, lB, acc);

    int lane = tid & 63, w = tid >> 6;
    int lr = lane & 15, lg = lane >> 4;
    int wm = (w & 1) * 64, wn = (w >> 1) * 64;
#pragma unroll
    for (int mi = 0; mi < 4; ++mi) {
#pragma unroll
        for (int ni = 0; ni < 4; ++ni) {
            int col = bx * BN + wn + ni * 16 + lr;
            float bvv = bias[col];
#pragma unroll
            for (int r = 0; r < 4; ++r) {
                int row = by * BM + wm + mi * 16 + 4 * lg + r;
                if (row >= M) continue;
                Cf[(size_t)row * N + col] = acc[mi][ni][r] + bvv;
            }
        }
    }
}

// ---------------------------------------------------------------------------
// Flash attention v8: 8-wave K-SPLIT (block=512). Wave wv takes k-tiles
// kt = wv, wv+8, ... with the verified inner loop. Partials merged by wave 0
// (f16x4 O-partials in LDS to keep occupancy: ~53 KB -> 3 blocks/CU).
__global__ __launch_bounds__(512) void attn_fwd(
    const f16* __restrict__ qh2, const f16* __restrict__ kh2,
    const f16* __restrict__ vt, const int* __restrict__ cu,
    f16* __restrict__ oh, int Spad, int nq, int Bn) {
    int wgid = blockIdx.x;
    int nbh = Bn * 16;
    int b, h, qi;
    if ((nbh & 7) == 0) {
        int xcd = wgid & 7, rest = wgid >> 3, nbh8 = nbh >> 3;
        int bhhi = rest % nbh8;
        qi = (nq - 1) - rest / nbh8;          // longest blocks first
        int bhv = (bhhi << 3) | xcd;
        b = bhv >> 4; h = bhv & 15;
    } else {
        qi = wgid % nq;
        int bhv = wgid / nq;
        b = bhv >> 4; h = bhv & 15;
    }
    int bh = b * 16 + h;
    int s0 = cu[b];
    int len = cu[b + 1] - s0;
    int q0 = qi * 32;
    if (q0 >= len) return;
    int tid = threadIdx.x;
    int wv = tid >> 6;                     // wave 0..7
    int lane = tid & 63, lr = lane & 15, lg = lane >> 4;
    __shared__ f16 pl[8][2][16][40];       // [wave][qt][q-row][k pad40]
    __shared__ float mlb[7][2][2][16];     // [wave-1][qt][{m,l}][q]
    __shared__ f16x4 owb[7][2][4][16][4];  // [wave-1][qt][dt][q=lr][lg] (f16 partials)

    const f16* qbase = qh2 + (size_t)bh * Spad * 64;
    const f16* kbase = kh2 + (size_t)bh * Spad * 64;
    const f16* vbase = vt  + (size_t)bh * 64 * Spad;

    f16x8 qf[2][2];
#pragma unroll
    for (int qt = 0; qt < 2; ++qt) {
        const f16* qp = qbase + (size_t)(q0 + 16 * qt + lr) * 64 + 8 * lg;
        qf[qt][0] = *reinterpret_cast<const f16x8*>(qp);
        qf[qt][1] = *reinterpret_cast<const f16x8*>(qp + 32);
    }
    float mrun[2] = {-1e30f, -1e30f}, lrun[2] = {0.f, 0.f};
    f32x4 oacc[2][4] = {};

    int kend = min(q0 + 32, len);
    int ntk = (kend + 31) >> 5;            // wave wv takes kt = wv, wv+8, ...

    f16x8 kf[2][2], kn[2][2];
#pragma unroll
    for (int j = 0; j < 2; ++j) {
        const f16* kp = kbase + (size_t)(wv * 32 + 16 * j + lr) * 64 + 8 * lg;
        kf[j][0] = *reinterpret_cast<const f16x8*>(kp);
        kf[j][1] = *reinterpret_cast<const f16x8*>(kp + 32);
    }

    for (int kt = wv; kt < ntk; kt += 8) {
        int kk0 = kt << 5;
        f16x8 vf[4];
#pragma unroll
        for (int dt = 0; dt < 4; ++dt)
            vf[dt] = *reinterpret_cast<const f16x8*>(
                vbase + (size_t)(16 * dt + lr) * Spad + kk0 + 8 * lg);
        f32x4 st[2][2];
#pragma unroll
        for (int qt = 0; qt < 2; ++qt)
#pragma unroll
            for (int j = 0; j < 2; ++j) {
                f32x4 z = {0, 0, 0, 0};
                z = MFMA16(kf[j][0], qf[qt][0], z);
                z = MFMA16(kf[j][1], qf[qt][1], z);
                st[qt][j] = z;
            }
        if (kt + 8 < ntk) {
#pragma unroll
            for (int j = 0; j < 2; ++j) {
                const f16* kp = kbase + (size_t)(kk0 + 256 + 16 * j + lr) * 64 + 8 * lg;
                kn[j][0] = *reinterpret_cast<const f16x8*>(kp);
                kn[j][1] = *reinterpret_cast<const f16x8*>(kp + 32);
            }
        }
#pragma unroll
        for (int qt = 0; qt < 2; ++qt) {
            int qr = q0 + 16 * qt + lr;
            float sv[2][4];
            float mx = -1e30f;
#pragma unroll
            for (int j = 0; j < 2; ++j)
#pragma unroll
                for (int r = 0; r < 4; ++r) {
                    int kc = kk0 + 16 * j + 4 * lg + r;
                    float v = st[qt][j][r];
                    if (kc > qr || kc >= len) v = -1e30f;
                    sv[j][r] = v;
                    mx = fmaxf(mx, v);
                }
            mx = fmaxf(mx, __shfl_xor(mx, 16, 64));
            mx = fmaxf(mx, __shfl_xor(mx, 32, 64));
            float mnew = fmaxf(mrun[qt], mx);
            float al = __expf(mrun[qt] - mnew);
            mrun[qt] = mnew;
            float rs = 0.f;
            f16x4 pk0, pk1;
#pragma unroll
            for (int r = 0; r < 4; ++r) {
                float p0 = __expf(sv[0][r] - mnew);
                float p1 = __expf(sv[1][r] - mnew);
                rs += p0 + p1;
                pk0[r] = (f16)p0;
                pk1[r] = (f16)p1;
            }
            rs += __shfl_xor(rs, 16, 64);
            rs += __shfl_xor(rs, 32, 64);
            lrun[qt] = lrun[qt] * al + rs;
            *reinterpret_cast<f16x4*>(&pl[wv][qt][lr][4 * lg])      = pk0;
            *reinterpret_cast<f16x4*>(&pl[wv][qt][lr][16 + 4 * lg]) = pk1;
#pragma unroll
            for (int dt = 0; dt < 4; ++dt)
#pragma unroll
                for (int r = 0; r < 4; ++r) oacc[qt][dt][r] *= al;
        }
        asm volatile("s_waitcnt lgkmcnt(0)" ::: "memory");
        __builtin_amdgcn_sched_barrier(0);
        f16x8 pa0 = *reinterpret_cast<const f16x8*>(&pl[wv][0][lr][8 * lg]);
        f16x8 pa1 = *reinterpret_cast<const f16x8*>(&pl[wv][1][lr][8 * lg]);
#pragma unroll
        for (int dt = 0; dt < 4; ++dt) {
            oacc[0][dt] = MFMA16(vf[dt], pa0, oacc[0][dt]);
            oacc[1][dt] = MFMA16(vf[dt], pa1, oacc[1][dt]);
        }
        asm volatile("" ::: "memory");
#pragma unroll
        for (int j = 0; j < 2; ++j) {
            kf[j][0] = kn[j][0];
            kf[j][1] = kn[j][1];
        }
    }

    // flash merge of 8 waves' partials (wave 0 accumulates)
    if (wv > 0) {
#pragma unroll
        for (int qt = 0; qt < 2; ++qt) {
            if (lg == 0) {
                mlb[wv - 1][qt][0][lr] = mrun[qt];
                mlb[wv - 1][qt][1][lr] = lrun[qt];
            }
#pragma unroll
            for (int dt = 0; dt < 4; ++dt) {
                f16x4 ov;
#pragma unroll
                for (int r = 0; r < 4; ++r) ov[r] = (f16)oacc[qt][dt][r];
                owb[wv - 1][qt][dt][lr][lg] = ov;
            }
        }
    }
    __syncthreads();
    if (wv == 0) {
#pragma unroll
        for (int qt = 0; qt < 2; ++qt) {
            int qr = q0 + 16 * qt + lr;
            if (qr >= len) continue;
            float m = mrun[qt];
#pragma unroll
            for (int i = 0; i < 7; ++i) m = fmaxf(m, mlb[i][qt][0][lr]);
            float a0 = __expf(mrun[qt] - m);
            float lsum = lrun[qt] * a0;
            float ai[7];
#pragma unroll
            for (int i = 0; i < 7; ++i) {
                ai[i] = __expf(mlb[i][qt][0][lr] - m);
                lsum += mlb[i][qt][1][lr] * ai[i];
            }
            float linv = 1.f / lsum;
            f16* orow = oh + (size_t)(s0 + qr) * 1024 + h * 64;
#pragma unroll
            for (int dt = 0; dt < 4; ++dt) {
                f16x4 ov;
#pragma unroll
                for (int r = 0; r < 4; ++r) {
                    float o = oacc[qt][dt][r] * a0;
#pragma unroll
                    for (int i = 0; i < 7; ++i)
                        o += (float)owb[i][qt][dt][lr][lg][r] * ai[i];
                    ov[r] = (f16)(o * linv);
                }
                *reinterpret_cast<f16x4*>(orow + 16 * dt + 4 * lg) = ov;
            }
        }
    }
}

// ---------------------------------------------------------------------------
extern "C" void kernel_launch(void* const* d_in, const int* in_sizes, int n_in,
                              void* d_out, int out_size, void* d_ws, size_t ws_size,
                              hipStream_t stream) {
    const float* x    = (const float*)d_in[0];
    const float* Wqkv = (const float*)d_in[1];
    const float* bqkv = (const float*)d_in[2];
    const float* Wo   = (const float*)d_in[3];
    const float* bo   = (const float*)d_in[4];
    const int*   cu   = (const int*)d_in[5];

    const int Dm = 1024;
    int T  = in_sizes[0] / Dm;
    int Bn = in_sizes[5] - 1;
    int Spad = 1024;  // max_seqlen

    auto al = [](size_t v) { return (v + 255) & ~(size_t)255; };
    char* w = (char*)d_ws;
    size_t off = 0;
    f16* xh     = (f16*)(w + off); off = al(off + (size_t)2 * T * 1024);
    f16* wqkvT  = (f16*)(w + off); off = al(off + (size_t)2 * 3072 * 1024);
    f16* woT    = (f16*)(w + off); off = al(off + (size_t)2 * 1024 * 1024);
    f16* qh2    = (f16*)(w + off); off = al(off + (size_t)2 * Bn * 16 * 64 * (size_t)Spad);
    f16* kh2    = (f16*)(w + off); off = al(off + (size_t)2 * Bn * 16 * 64 * (size_t)Spad);
    f16* vtp    = (f16*)(w + off); off = al(off + (size_t)2 * Bn * 16 * 64 * (size_t)Spad);
    f16* ohp    = (f16*)(w + off); off = al(off + (size_t)2 * T * 1024);
    float2* tab = (float2*)(w + off); off = al(off + (size_t)8 * Spad * 32);
    int* bpos   = (int*)(w + off);   off = al(off + (size_t)4 * T);
    (void)ws_size;

    // 1. prep: weight transposes + trig table + x->fp16 + bpos table
    {
        int nb = 1152 + T + (T + 255) / 256;
        prep<<<nb, 256, 0, stream>>>(x, xh, T, Wqkv, Wo, wqkvT, woT, tab, Spad,
                                     cu, Bn, bpos);
    }
    // 2. QKV GEMM with fused bias+RoPE+scatter epilogue
    {
        int nbx = 3072 / BN, nby = (T + BM - 1) / BM;
        gemm_qkv<<<nbx * nby, 256, 0, stream>>>(xh, wqkvT, bqkv, bpos, tab,
                                                T, Spad, qh2, kh2, vtp, nbx);
    }
    // 3. attention (8-wave K-split)
    {
        int nq = Spad / 32;
        int ngrid = nq * 16 * Bn;
        attn_fwd<<<ngrid, 512, 0, stream>>>(qh2, kh2, vtp, cu, ohp, Spad, nq, Bn);
    }
    // 4. out-proj GEMM -> fp32 d_out
    {
        int nbx = 1024 / BN, nby = (T + BM - 1) / BM;
        gemm_out<<<nbx * nby, 256, 0, stream>>>(ohp, woT, bo, (float*)d_out,
                                                T, 1024, 1024, nbx);
    }
}

// Round 16
// 119.303 us; speedup vs baseline: 1.0522x; 1.0522x over previous
//
#include <hip/hip_runtime.h>

typedef _Float16 f16;
typedef _Float16 f16x8 __attribute__((ext_vector_type(8)));
typedef _Float16 f16x4 __attribute__((ext_vector_type(4)));
typedef float f32x4 __attribute__((ext_vector_type(4)));

#define BM 128
#define BN 128
#define BKK 32

#define MFMA16(a, b, c) __builtin_amdgcn_mfma_f32_16x16x32_f16((a), (b), (c), 0, 0, 0)

typedef __attribute__((address_space(3))) void lds_void;
typedef const __attribute__((address_space(1))) void g_void;
__device__ __forceinline__ void async_copy16(void* lds, const void* g) {
    __builtin_amdgcn_global_load_lds((g_void*)g, (lds_void*)lds, 16, 0, 0);
}

// ---------------------------------------------------------------------------
// prep: fused (a) wtrans Wqkv+Wo (b) RoPE trig table (c) x fp32->fp16
//       (d) bpos[t] = (seq_id<<16)|pos token table.
__global__ __launch_bounds__(256) void prep(
    const float* __restrict__ x, f16* __restrict__ xh, int T,
    const float* __restrict__ Wqkv, const float* __restrict__ Wo,
    f16* __restrict__ wqkvT, f16* __restrict__ woT,
    float2* __restrict__ tab, int Spad,
    const int* __restrict__ cu, int Bn, int* __restrict__ bpos) {
    int id = blockIdx.x;
    int tid = threadIdx.x;
    if (id < 1024) {
        __shared__ f16 tile[64][65];
        const float* in; f16* out; int N, bx, by;
        if (id < 768) { in = Wqkv; out = wqkvT; N = 3072; bx = id % 48; by = id / 48; }
        else { int j = id - 768; in = Wo; out = woT; N = 1024; bx = j % 16; by = j / 16; }
        const int K = 1024;
        int n0 = bx * 64, k0 = by * 64;
        int c = tid & 63, rb = tid >> 6;
#pragma unroll
        for (int it = 0; it < 16; ++it) {
            int r = rb + it * 4;
            tile[r][c] = (f16)in[(size_t)(k0 + r) * N + n0 + c];
        }
        __syncthreads();
#pragma unroll
        for (int it = 0; it < 16; ++it) {
            int rr = rb + it * 4;
            out[(size_t)(n0 + rr) * K + k0 + c] = tile[c][rr];
        }
    } else if (id < 1152) {
        int idx = (id - 1024) * 256 + tid;
        if (idx < Spad * 32) {
            int pos = idx >> 5, i = idx & 31;
            float inv = exp2f((float)i * (-13.287712379549449f / 32.f));
            float sn, cs;
            __sincosf((float)pos * inv, &sn, &cs);
            tab[idx] = make_float2(cs, sn);
        }
    } else if (id < 1152 + T) {
        int i4 = ((id - 1152) * 256 + tid) * 4;
        if (i4 < T * 1024) {
            float4 v = *reinterpret_cast<const float4*>(x + i4);
            f16x4 o;
            o[0] = (f16)v.x; o[1] = (f16)v.y; o[2] = (f16)v.z; o[3] = (f16)v.w;
            *reinterpret_cast<f16x4*>(xh + i4) = o;
        }
    } else {
        int t = (id - 1152 - T) * 256 + tid;
        if (t < T) {
            int b = 0, pos = t;
            for (int q = 0; q < Bn; ++q) {
                int lo = cu[q], hi = cu[q + 1];
                if (t >= lo && t < hi) { b = q; pos = t - lo; break; }
            }
            bpos[t] = (b << 16) | pos;
        }
    }
}

// ---------------------------------------------------------------------------
// shared m97-structure GEMM main loop with bank-conflict XOR swizzle.
// LDS[row][chunk] holds G[row][chunk ^ ((row>>1)&3)] (16B chunks, involution):
// staging source pre-swizzled, fragment reads swizzle back.
__device__ __forceinline__ void gemm_core(
    const f16* __restrict__ A, const f16* __restrict__ Bt,
    int M, int N, int K, int bx, int by, int tid,
    f16 lA[2][BM * BKK], f16 lB[2][BN * BKK], f32x4 acc[4][4]) {
    int lane = tid & 63, w = tid >> 6;
    int lr = lane & 15, lg = lane >> 4;
    int wm = (w & 1) * 64, wn = (w >> 1) * 64;
    int srow = tid >> 2;
    int scol = (((tid & 3) ^ ((tid >> 3) & 3)) * 8);   // pre-swizzled source chunk
    const f16* ga0 = A  + (size_t)min(by * BM + srow,      M - 1) * K + scol;
    const f16* ga1 = A  + (size_t)min(by * BM + 64 + srow, M - 1) * K + scol;
    const f16* gb0 = Bt + (size_t)min(bx * BN + srow,      N - 1) * K + scol;
    const f16* gb1 = Bt + (size_t)min(bx * BN + 64 + srow, N - 1) * K + scol;
    int NT = K / BKK;
    int csw = (lg ^ ((lr >> 1) & 3)) * 8;              // swizzled read chunk
#define STAGE(curb, kt) do {                                        \
        int ko = (kt) * BKK;                                        \
        async_copy16(&lA[curb][w * 512],        ga0 + ko);          \
        async_copy16(&lA[curb][2048 + w * 512], ga1 + ko);          \
        async_copy16(&lB[curb][w * 512],        gb0 + ko);          \
        async_copy16(&lB[curb][2048 + w * 512], gb1 + ko);          \
    } while (0)
    STAGE(0, 0);
    __syncthreads();
    int cur = 0;
    for (int kt = 0; kt < NT; ++kt) {
        if (kt + 1 < NT) STAGE(cur ^ 1, kt + 1);
        f16x8 af[4], bf[4];
#pragma unroll
        for (int i = 0; i < 4; ++i) {
            af[i] = *reinterpret_cast<const f16x8*>(&lA[cur][(wm + i * 16 + lr) * BKK + csw]);
            bf[i] = *reinterpret_cast<const f16x8*>(&lB[cur][(wn + i * 16 + lr) * BKK + csw]);
        }
#pragma unroll
        for (int mi = 0; mi < 4; ++mi)
#pragma unroll
            for (int ni = 0; ni < 4; ++ni)
                acc[mi][ni] = MFMA16(af[mi], bf[ni], acc[mi][ni]);
        __syncthreads();
        cur ^= 1;
    }
#undef STAGE
}

// ---------------------------------------------------------------------------
// QKV GEMM with fused bias + RoPE + head-major scatter epilogue (bpos table).
__global__ __launch_bounds__(256) void gemm_qkv(
    const f16* __restrict__ A, const f16* __restrict__ Bt,
    const float* __restrict__ bias, const int* __restrict__ bpos,
    const float2* __restrict__ tab, int M, int Spad,
    f16* __restrict__ qh2, f16* __restrict__ kh2, f16* __restrict__ vt, int nbx) {
    __shared__ f16 lA[2][BM * BKK];
    __shared__ f16 lB[2][BN * BKK];
    int tid = threadIdx.x;
    int nwg = gridDim.x, wg = blockIdx.x;
    int tile = ((nwg & 7) == 0) ? ((wg & 7) * (nwg >> 3) + (wg >> 3)) : wg;
    int by = tile / nbx, bx = tile % nbx;

    f32x4 acc[4][4] = {};
    gemm_core(A, Bt, M, 3072, 1024, bx, by, tid, lA, lB, acc);

    int lane = tid & 63, w = tid >> 6;
    int lr = lane & 15, lg = lane >> 4;
    int wm = (w & 1) * 64, wn = (w >> 1) * 64;
    int colwave = bx * BN + wn;          // multiple of 64
    int sect = colwave >> 10;            // 0=q, 1=k, 2=v
    int h = (colwave & 1023) >> 6;
    float bv[4];
#pragma unroll
    for (int ni = 0; ni < 4; ++ni) bv[ni] = bias[colwave + ni * 16 + lr];

#pragma unroll
    for (int mi = 0; mi < 4; ++mi) {
        int row0 = by * BM + wm + mi * 16 + 4 * lg;
        if (row0 >= M) continue;
        if (sect == 2) {
            int v0 = bpos[row0];
            int b0 = v0 >> 16, p0 = v0 & 0xffff;
            bool pack = (row0 + 3 < M) && ((p0 & 3) == 0) && ((bpos[row0 + 3] >> 16) == b0);
            if (pack) {
                size_t vb = (size_t)(b0 * 16 + h) * 64;
#pragma unroll
                for (int ni = 0; ni < 4; ++ni) {
                    int d = ni * 16 + lr;
                    f16x4 ov;
#pragma unroll
                    for (int r = 0; r < 4; ++r) ov[r] = (f16)(acc[mi][ni][r] + bv[ni]);
                    *reinterpret_cast<f16x4*>(vt + (vb + d) * Spad + p0) = ov;
                }
            } else {
                for (int r = 0; r < 4; ++r) {
                    int row = row0 + r;
                    if (row >= M) break;
                    int v = bpos[row];
                    int b = v >> 16, pos = v & 0xffff;
                    size_t vb = (size_t)(b * 16 + h) * 64;
#pragma unroll
                    for (int ni = 0; ni < 4; ++ni)
                        vt[(vb + ni * 16 + lr) * Spad + pos] = (f16)(acc[mi][ni][r] + bv[ni]);
                }
            }
        } else {
            float sc = sect == 0 ? 0.125f : 1.f;
            f16* dstbase = sect == 0 ? qh2 : kh2;
            for (int r = 0; r < 4; ++r) {
                int row = row0 + r;
                if (row >= M) break;
                int v = bpos[row];
                int b = v >> 16, pos = v & 0xffff;
                const float2* tb = tab + pos * 32;
                f16* dst = dstbase + ((size_t)(b * 16 + h) * Spad + pos) * 64;
#pragma unroll
                for (int p = 0; p < 2; ++p) {
                    int i = p * 16 + lr;
                    float2 csn = tb[i];
                    float v1 = acc[mi][p][r] + bv[p];
                    float v2 = acc[mi][p + 2][r] + bv[p + 2];
                    dst[i]      = (f16)((v1 * csn.x - v2 * csn.y) * sc);
                    dst[i + 32] = (f16)((v2 * csn.x + v1 * csn.y) * sc);
                }
            }
        }
    }
}

// ---------------------------------------------------------------------------
// out-proj GEMM: plain epilogue, fp32 out + bias.
__global__ __launch_bounds__(256) void gemm_out(
    const f16* __restrict__ A, const f16* __restrict__ Bt,
    const float* __restrict__ bias, float* __restrict__ Cf,
    int M, int N, int K, int nbx) {
    __shared__ f16 lA[2][BM * BKK];
    __shared__ f16 lB[2][BN * BKK];
    int tid = threadIdx.x;
    int nwg = gridDim.x, wg = blockIdx.x;
    int tile = ((nwg & 7) == 0) ? ((wg & 7) * (nwg >> 3) + (wg >> 3)) : wg;
    int by = tile / nbx, bx = tile % nbx;

    f32x4 acc[4][4] = {};
    gemm_core(A, Bt, M, N, K, bx, by, tid, lA, lB, acc);

    int lane = tid & 63, w = tid >> 6;
    int lr = lane & 15, lg = lane >> 4;
    int wm = (w & 1) * 64, wn = (w >> 1) * 64;
#pragma unroll
    for (int mi = 0; mi < 4; ++mi) {
#pragma unroll
        for (int ni = 0; ni < 4; ++ni) {
            int col = bx * BN + wn + ni * 16 + lr;
            float bvv = bias[col];
#pragma unroll
            for (int r = 0; r < 4; ++r) {
                int row = by * BM + wm + mi * 16 + 4 * lg + r;
                if (row >= M) continue;
                Cf[(size_t)row * N + col] = acc[mi][ni][r] + bvv;
            }
        }
    }
}

// ---------------------------------------------------------------------------
// Flash attention v7 (r14 verbatim): 4-wave K-SPLIT. Block = 256 threads.
// Wave wv processes k-tiles kt = wv, wv+4, ... with the verified inner loop
// (QBLK=32, KVBLK=32, swapped operands, lane-local softmax, K dbuf, V
// prefetch, wave-local P round-trip with inline lgkmcnt fence). Flash merge
// of 4 partials. Bijective XCD-affinity remap, longest-first.
__global__ __launch_bounds__(256) void attn_fwd(
    const f16* __restrict__ qh2, const f16* __restrict__ kh2,
    const f16* __restrict__ vt, const int* __restrict__ cu,
    f16* __restrict__ oh, int Spad, int nq, int Bn) {
    int wgid = blockIdx.x;
    int nbh = Bn * 16;
    int b, h, qi;
    if ((nbh & 7) == 0) {
        int xcd = wgid & 7, rest = wgid >> 3, nbh8 = nbh >> 3;
        int bhhi = rest % nbh8;
        qi = (nq - 1) - rest / nbh8;          // longest blocks first
        int bhv = (bhhi << 3) | xcd;
        b = bhv >> 4; h = bhv & 15;
    } else {
        qi = wgid % nq;
        int bhv = wgid / nq;
        b = bhv >> 4; h = bhv & 15;
    }
    int bh = b * 16 + h;
    int s0 = cu[b];
    int len = cu[b + 1] - s0;
    int q0 = qi * 32;
    if (q0 >= len) return;
    int tid = threadIdx.x;
    int wv = tid >> 6;                     // wave 0..3
    int lane = tid & 63, lr = lane & 15, lg = lane >> 4;
    __shared__ f16 pl[4][2][16][40];       // [wave][qt][q-row][k pad40]
    __shared__ float mlb[3][2][2][16];     // [wave-1][qt][{m,l}][q]
    __shared__ f32x4 owb[3][2][4][16][4];  // [wave-1][qt][dt][q=lr][lg]

    const f16* qbase = qh2 + (size_t)bh * Spad * 64;
    const f16* kbase = kh2 + (size_t)bh * Spad * 64;
    const f16* vbase = vt  + (size_t)bh * 64 * Spad;

    f16x8 qf[2][2];
#pragma unroll
    for (int qt = 0; qt < 2; ++qt) {
        const f16* qp = qbase + (size_t)(q0 + 16 * qt + lr) * 64 + 8 * lg;
        qf[qt][0] = *reinterpret_cast<const f16x8*>(qp);
        qf[qt][1] = *reinterpret_cast<const f16x8*>(qp + 32);
    }
    float mrun[2] = {-1e30f, -1e30f}, lrun[2] = {0.f, 0.f};
    f32x4 oacc[2][4] = {};

    int kend = min(q0 + 32, len);
    int ntk = (kend + 31) >> 5;            // wave wv takes kt = wv, wv+4, ...

    f16x8 kf[2][2], kn[2][2];
#pragma unroll
    for (int j = 0; j < 2; ++j) {
        const f16* kp = kbase + (size_t)(wv * 32 + 16 * j + lr) * 64 + 8 * lg;
        kf[j][0] = *reinterpret_cast<const f16x8*>(kp);
        kf[j][1] = *reinterpret_cast<const f16x8*>(kp + 32);
    }

    for (int kt = wv; kt < ntk; kt += 4) {
        int kk0 = kt << 5;
        f16x8 vf[4];
#pragma unroll
        for (int dt = 0; dt < 4; ++dt)
            vf[dt] = *reinterpret_cast<const f16x8*>(
                vbase + (size_t)(16 * dt + lr) * Spad + kk0 + 8 * lg);
        f32x4 st[2][2];
#pragma unroll
        for (int qt = 0; qt < 2; ++qt)
#pragma unroll
            for (int j = 0; j < 2; ++j) {
                f32x4 z = {0, 0, 0, 0};
                z = MFMA16(kf[j][0], qf[qt][0], z);
                z = MFMA16(kf[j][1], qf[qt][1], z);
                st[qt][j] = z;
            }
        if (kt + 4 < ntk) {
#pragma unroll
            for (int j = 0; j < 2; ++j) {
                const f16* kp = kbase + (size_t)(kk0 + 128 + 16 * j + lr) * 64 + 8 * lg;
                kn[j][0] = *reinterpret_cast<const f16x8*>(kp);
                kn[j][1] = *reinterpret_cast<const f16x8*>(kp + 32);
            }
        }
#pragma unroll
        for (int qt = 0; qt < 2; ++qt) {
            int qr = q0 + 16 * qt + lr;
            float sv[2][4];
            float mx = -1e30f;
#pragma unroll
            for (int j = 0; j < 2; ++j)
#pragma unroll
                for (int r = 0; r < 4; ++r) {
                    int kc = kk0 + 16 * j + 4 * lg + r;
                    float v = st[qt][j][r];
                    if (kc > qr || kc >= len) v = -1e30f;
                    sv[j][r] = v;
                    mx = fmaxf(mx, v);
                }
            mx = fmaxf(mx, __shfl_xor(mx, 16, 64));
            mx = fmaxf(mx, __shfl_xor(mx, 32, 64));
            float mnew = fmaxf(mrun[qt], mx);
            float al = __expf(mrun[qt] - mnew);
            mrun[qt] = mnew;
            float rs = 0.f;
            f16x4 pk0, pk1;
#pragma unroll
            for (int r = 0; r < 4; ++r) {
                float p0 = __expf(sv[0][r] - mnew);
                float p1 = __expf(sv[1][r] - mnew);
                rs += p0 + p1;
                pk0[r] = (f16)p0;
                pk1[r] = (f16)p1;
            }
            rs += __shfl_xor(rs, 16, 64);
            rs += __shfl_xor(rs, 32, 64);
            lrun[qt] = lrun[qt] * al + rs;
            *reinterpret_cast<f16x4*>(&pl[wv][qt][lr][4 * lg])      = pk0;
            *reinterpret_cast<f16x4*>(&pl[wv][qt][lr][16 + 4 * lg]) = pk1;
#pragma unroll
            for (int dt = 0; dt < 4; ++dt)
#pragma unroll
                for (int r = 0; r < 4; ++r) oacc[qt][dt][r] *= al;
        }
        asm volatile("s_waitcnt lgkmcnt(0)" ::: "memory");
        __builtin_amdgcn_sched_barrier(0);
        f16x8 pa0 = *reinterpret_cast<const f16x8*>(&pl[wv][0][lr][8 * lg]);
        f16x8 pa1 = *reinterpret_cast<const f16x8*>(&pl[wv][1][lr][8 * lg]);
#pragma unroll
        for (int dt = 0; dt < 4; ++dt) {
            oacc[0][dt] = MFMA16(vf[dt], pa0, oacc[0][dt]);
            oacc[1][dt] = MFMA16(vf[dt], pa1, oacc[1][dt]);
        }
        asm volatile("" ::: "memory");
#pragma unroll
        for (int j = 0; j < 2; ++j) {
            kf[j][0] = kn[j][0];
            kf[j][1] = kn[j][1];
        }
    }

    // flash merge of 4 waves' partials
    if (wv > 0) {
#pragma unroll
        for (int qt = 0; qt < 2; ++qt) {
            if (lg == 0) {
                mlb[wv - 1][qt][0][lr] = mrun[qt];
                mlb[wv - 1][qt][1][lr] = lrun[qt];
            }
#pragma unroll
            for (int dt = 0; dt < 4; ++dt)
                owb[wv - 1][qt][dt][lr][lg] = oacc[qt][dt];
        }
    }
    __syncthreads();
    if (wv == 0) {
#pragma unroll
        for (int qt = 0; qt < 2; ++qt) {
            int qr = q0 + 16 * qt + lr;
            if (qr >= len) continue;
            float m = mrun[qt];
#pragma unroll
            for (int i = 0; i < 3; ++i) m = fmaxf(m, mlb[i][qt][0][lr]);
            float a0 = __expf(mrun[qt] - m);
            float lsum = lrun[qt] * a0;
            float ai[3];
#pragma unroll
            for (int i = 0; i < 3; ++i) {
                ai[i] = __expf(mlb[i][qt][0][lr] - m);
                lsum += mlb[i][qt][1][lr] * ai[i];
            }
            float linv = 1.f / lsum;
            f16* orow = oh + (size_t)(s0 + qr) * 1024 + h * 64;
#pragma unroll
            for (int dt = 0; dt < 4; ++dt) {
                f16x4 ov;
#pragma unroll
                for (int r = 0; r < 4; ++r) {
                    float o = oacc[qt][dt][r] * a0;
#pragma unroll
                    for (int i = 0; i < 3; ++i) o += owb[i][qt][dt][lr][lg][r] * ai[i];
                    ov[r] = (f16)(o * linv);
                }
                *reinterpret_cast<f16x4*>(orow + 16 * dt + 4 * lg) = ov;
            }
        }
    }
}

// ---------------------------------------------------------------------------
extern "C" void kernel_launch(void* const* d_in, const int* in_sizes, int n_in,
                              void* d_out, int out_size, void* d_ws, size_t ws_size,
                              hipStream_t stream) {
    const float* x    = (const float*)d_in[0];
    const float* Wqkv = (const float*)d_in[1];
    const float* bqkv = (const float*)d_in[2];
    const float* Wo   = (const float*)d_in[3];
    const float* bo   = (const float*)d_in[4];
    const int*   cu   = (const int*)d_in[5];

    const int Dm = 1024;
    int T  = in_sizes[0] / Dm;
    int Bn = in_sizes[5] - 1;
    int Spad = 1024;  // max_seqlen

    auto al = [](size_t v) { return (v + 255) & ~(size_t)255; };
    char* w = (char*)d_ws;
    size_t off = 0;
    f16* xh     = (f16*)(w + off); off = al(off + (size_t)2 * T * 1024);
    f16* wqkvT  = (f16*)(w + off); off = al(off + (size_t)2 * 3072 * 1024);
    f16* woT    = (f16*)(w + off); off = al(off + (size_t)2 * 1024 * 1024);
    f16* qh2    = (f16*)(w + off); off = al(off + (size_t)2 * Bn * 16 * 64 * (size_t)Spad);
    f16* kh2    = (f16*)(w + off); off = al(off + (size_t)2 * Bn * 16 * 64 * (size_t)Spad);
    f16* vtp    = (f16*)(w + off); off = al(off + (size_t)2 * Bn * 16 * 64 * (size_t)Spad);
    f16* ohp    = (f16*)(w + off); off = al(off + (size_t)2 * T * 1024);
    float2* tab = (float2*)(w + off); off = al(off + (size_t)8 * Spad * 32);
    int* bpos   = (int*)(w + off);   off = al(off + (size_t)4 * T);
    (void)ws_size;

    // 1. prep: weight transposes + trig table + x->fp16 + bpos table
    {
        int nb = 1152 + T + (T + 255) / 256;
        prep<<<nb, 256, 0, stream>>>(x, xh, T, Wqkv, Wo, wqkvT, woT, tab, Spad,
                                     cu, Bn, bpos);
    }
    // 2. QKV GEMM with fused bias+RoPE+scatter epilogue
    {
        int nbx = 3072 / BN, nby = (T + BM - 1) / BM;
        gemm_qkv<<<nbx * nby, 256, 0, stream>>>(xh, wqkvT, bqkv, bpos, tab,
                                                T, Spad, qh2, kh2, vtp, nbx);
    }
    // 3. attention (4-wave K-split, r14 verbatim)
    {
        int nq = Spad / 32;
        int ngrid = nq * 16 * Bn;
        attn_fwd<<<ngrid, 256, 0, stream>>>(qh2, kh2, vtp, cu, ohp, Spad, nq, Bn);
    }
    // 4. out-proj GEMM -> fp32 d_out
    {
        int nbx = 1024 / BN, nby = (T + BM - 1) / BM;
        gemm_out<<<nbx * nby, 256, 0, stream>>>(ohp, woT, bo, (float*)d_out,
                                                T, 1024, 1024, nbx);
    }
}